// Round 1
// baseline (1697.132 us; speedup 1.0000x reference)
//
#include <hip/hip_runtime.h>
#include <stdint.h>

// ---------- types ----------
typedef __bf16 bf16x8 __attribute__((ext_vector_type(8)));
typedef float  f32x4  __attribute__((ext_vector_type(4)));
typedef unsigned short ushortx8 __attribute__((ext_vector_type(8)));
typedef unsigned short ushortx4 __attribute__((ext_vector_type(4)));

#define DEVI __device__ __forceinline__

DEVI unsigned short f2bf(float f) {
  union { float f; unsigned int u; } v; v.f = f;
  unsigned int r = v.u + 0x7fffu + ((v.u >> 16) & 1u);
  return (unsigned short)(r >> 16);
}
DEVI float bf2f(unsigned short h) {
  union { unsigned int u; float f; } v; v.u = ((unsigned int)h) << 16;
  return v.f;
}

// async global->LDS, 16B per lane (m97 structure)
DEVI void gl_lds16(const unsigned short* g, unsigned short* l) {
  __builtin_amdgcn_global_load_lds(
      (__attribute__((address_space(1))) unsigned int*)g,
      (__attribute__((address_space(3))) unsigned int*)l,
      16, 0, 0);
}

DEVI void store_out(float* p, float v) { *p = v; }
DEVI void store_out(unsigned short* p, float v) { *p = f2bf(v); }

// ---------- GroupNorm stats: one block per (batch, group) ----------
// x is [B,512,4096]; a group = 16 contiguous channels = 65536 contiguous floats
__global__ __launch_bounds__(256) void gn_stats(const float* __restrict__ x,
                                                float* __restrict__ stats) {
  const int bg = blockIdx.x;
  const float* p = x + (size_t)bg * 65536;
  const int tid = threadIdx.x;
  float s = 0.f, ss = 0.f;
#pragma unroll 4
  for (int i = 0; i < 64; ++i) {
    float4 v = *(const float4*)(p + (((size_t)i * 256 + tid) << 2));
    s  += v.x + v.y + v.z + v.w;
    ss += v.x * v.x + v.y * v.y + v.z * v.z + v.w * v.w;
  }
  for (int off = 32; off; off >>= 1) { s += __shfl_xor(s, off); ss += __shfl_xor(ss, off); }
  __shared__ float rs[4], rss[4];
  const int lane = tid & 63, wave = tid >> 6;
  if (lane == 0) { rs[wave] = s; rss[wave] = ss; }
  __syncthreads();
  if (tid == 0) {
    float S1 = rs[0] + rs[1] + rs[2] + rs[3];
    float S2 = rss[0] + rss[1] + rss[2] + rss[3];
    float mean = S1 * (1.f / 65536.f);
    float var  = S2 * (1.f / 65536.f) - mean * mean;
    stats[bg * 2 + 0] = mean;
    stats[bg * 2 + 1] = rsqrtf(var + 1e-5f);
  }
}

// ---------- GN apply + transpose to token-major bf16 h_t[B,4096,512] ----------
__global__ __launch_bounds__(256) void gn_apply(const float* __restrict__ x,
                                                const float* __restrict__ stats,
                                                const float* __restrict__ gamma,
                                                const float* __restrict__ beta,
                                                unsigned short* __restrict__ h_t) {
  __shared__ alignas(16) unsigned short tile[64 * 136];  // [tok][ch], pad 8
  const int tid = threadIdx.x;
  const int t0 = blockIdx.x * 64;    // token tile
  const int c0 = blockIdx.y * 128;   // channel tile
  const int b  = blockIdx.z;
  const float* xb = x + ((size_t)b * 512 + c0) * 4096 + t0;
#pragma unroll
  for (int j = 0; j < 8; ++j) {
    int f = tid + j * 256;
    int r = f >> 4;               // channel row 0..127
    int tc = (f & 15) << 2;       // token col 0..60
    float4 v = *(const float4*)(xb + (size_t)r * 4096 + tc);
    int ch = c0 + r;
    int g = ch >> 4;
    float mean = stats[((size_t)b * 32 + g) * 2 + 0];
    float rstd = stats[((size_t)b * 32 + g) * 2 + 1];
    float ga = gamma[ch] * rstd;
    float be = beta[ch] - mean * ga;
    tile[(tc + 0) * 136 + r] = f2bf(v.x * ga + be);
    tile[(tc + 1) * 136 + r] = f2bf(v.y * ga + be);
    tile[(tc + 2) * 136 + r] = f2bf(v.z * ga + be);
    tile[(tc + 3) * 136 + r] = f2bf(v.w * ga + be);
  }
  __syncthreads();
  unsigned short* hb = h_t + (size_t)b * 4096 * 512;
#pragma unroll
  for (int j = 0; j < 4; ++j) {
    int f = tid + j * 256;
    int tok = f >> 4;
    int cc = (f & 15) << 3;
    ushortx8 v = *(const ushortx8*)&tile[tok * 136 + cc];
    *(ushortx8*)(hb + (size_t)(t0 + tok) * 512 + c0 + cc) = v;
  }
}

// ---------- fp32 -> bf16 weight convert (262144 elems) ----------
__global__ __launch_bounds__(256) void cvt_f32_bf16(const float* __restrict__ s,
                                                    unsigned short* __restrict__ d) {
  int i = (blockIdx.x * 256 + threadIdx.x) * 4;
  float4 v = *(const float4*)(s + i);
  ushortx4 o;
  o[0] = f2bf(v.x); o[1] = f2bf(v.y); o[2] = f2bf(v.z); o[3] = f2bf(v.w);
  *(ushortx4*)(d + i) = o;
}

// ---------- NT-form MFMA GEMM: D[m,n] = alpha * sum_k A[m,k]*B[n,k] (+bias)(+resid)
// A: [M,K] row-major bf16, B: [N,K] row-major bf16. BM=BN=128, BK=32, 256 thr.
template <int BIAS_MODE, int RESID, typename OT>
__global__ __launch_bounds__(256) void gemm_nt(
    const unsigned short* __restrict__ A, const unsigned short* __restrict__ B,
    OT* __restrict__ D, const float* __restrict__ bias,
    const float* __restrict__ resid, int M, int N, int K,
    long long sA, long long sB, long long sD, long long sR, float alpha) {
  __shared__ alignas(16) unsigned short As[128 * 32];
  __shared__ alignas(16) unsigned short Bs[128 * 32];

  const int tid = threadIdx.x;
  const int bn = blockIdx.x, bm = blockIdx.y, bz = blockIdx.z;
  const unsigned short* Ab = A + (size_t)bz * sA + (size_t)bm * 128 * K;
  const unsigned short* Bb = B + (size_t)bz * sB + (size_t)bn * 128 * K;

  const int lane = tid & 63, wave = tid >> 6;
  const int wr = (wave >> 1) * 64, wc = (wave & 1) * 64;
  const int quad = lane >> 4, ln = lane & 15;

  const int r0 = tid >> 2, r1 = (tid + 256) >> 2;
  const int cc = (tid & 3) << 3;  // same for both halves

  f32x4 acc[4][4] = {};

  const int KT = K >> 5;
  for (int kt = 0; kt < KT; ++kt) {
    const size_t k0 = (size_t)kt << 5;
    const unsigned short* ag = Ab + k0;
    const unsigned short* bg = Bb + k0;
    gl_lds16(ag + (size_t)r0 * K + cc, &As[(size_t)tid << 3]);
    gl_lds16(ag + (size_t)r1 * K + cc, &As[(size_t)(tid + 256) << 3]);
    gl_lds16(bg + (size_t)r0 * K + cc, &Bs[(size_t)tid << 3]);
    gl_lds16(bg + (size_t)r1 * K + cc, &Bs[(size_t)(tid + 256) << 3]);
    __builtin_amdgcn_s_waitcnt(0);
    __syncthreads();

    bf16x8 af[4], bq[4];
#pragma unroll
    for (int mi = 0; mi < 4; ++mi)
      af[mi] = *(const bf16x8*)&As[(wr + mi * 16 + ln) * 32 + quad * 8];
#pragma unroll
    for (int ni = 0; ni < 4; ++ni)
      bq[ni] = *(const bf16x8*)&Bs[(wc + ni * 16 + ln) * 32 + quad * 8];
#pragma unroll
    for (int mi = 0; mi < 4; ++mi)
#pragma unroll
      for (int ni = 0; ni < 4; ++ni)
        acc[mi][ni] = __builtin_amdgcn_mfma_f32_16x16x32_bf16(af[mi], bq[ni],
                                                              acc[mi][ni], 0, 0, 0);
    __syncthreads();
  }

  OT* Db = D + (size_t)bz * sD;
  const float* Rb = RESID ? (resid + (size_t)bz * sR) : nullptr;
#pragma unroll
  for (int mi = 0; mi < 4; ++mi) {
#pragma unroll
    for (int ni = 0; ni < 4; ++ni) {
#pragma unroll
      for (int r = 0; r < 4; ++r) {
        int row = bm * 128 + wr + mi * 16 + quad * 4 + r;
        int col = bn * 128 + wc + ni * 16 + ln;
        float v = acc[mi][ni][r] * alpha;
        if (BIAS_MODE == 1) v += bias[row];
        if (BIAS_MODE == 2) v += bias[col];
        size_t idx = (size_t)row * N + col;
        if (RESID) v += Rb[idx];
        store_out(&Db[idx], v);
      }
    }
  }
}

// ---------- row softmax over 4096 bf16, in place ----------
__global__ __launch_bounds__(256) void softmax_rows(unsigned short* __restrict__ S) {
  const int tid = threadIdx.x;
  unsigned short* p = S + (size_t)blockIdx.x * 4096 + tid * 16;
  ushortx8 u0 = *(const ushortx8*)p;
  ushortx8 u1 = *(const ushortx8*)(p + 8);
  float v[16];
#pragma unroll
  for (int i = 0; i < 8; ++i) { v[i] = bf2f(u0[i]); v[i + 8] = bf2f(u1[i]); }
  float m = v[0];
#pragma unroll
  for (int i = 1; i < 16; ++i) m = fmaxf(m, v[i]);
  for (int off = 32; off; off >>= 1) m = fmaxf(m, __shfl_xor(m, off));
  __shared__ float red[4];
  __shared__ float red2[4];
  const int lane = tid & 63, wave = tid >> 6;
  if (lane == 0) red[wave] = m;
  __syncthreads();
  m = fmaxf(fmaxf(red[0], red[1]), fmaxf(red[2], red[3]));
  float s = 0.f;
#pragma unroll
  for (int i = 0; i < 16; ++i) { v[i] = __expf(v[i] - m); s += v[i]; }
  for (int off = 32; off; off >>= 1) s += __shfl_xor(s, off);
  if (lane == 0) red2[wave] = s;
  __syncthreads();
  s = red2[0] + red2[1] + red2[2] + red2[3];
  float inv = 1.f / s;
#pragma unroll
  for (int i = 0; i < 8; ++i) { u0[i] = f2bf(v[i] * inv); u1[i] = f2bf(v[i + 8] * inv); }
  *(ushortx8*)p = u0;
  *(ushortx8*)(p + 8) = u1;
}

// ---------- host ----------
extern "C" void kernel_launch(void* const* d_in, const int* in_sizes, int n_in,
                              void* d_out, int out_size, void* d_ws, size_t ws_size,
                              hipStream_t stream) {
  const float* x   = (const float*)d_in[0];
  const float* gnw = (const float*)d_in[1];
  const float* gnb = (const float*)d_in[2];
  const float* wq  = (const float*)d_in[3];
  const float* bq  = (const float*)d_in[4];
  const float* wk  = (const float*)d_in[5];
  const float* bk  = (const float*)d_in[6];
  const float* wv  = (const float*)d_in[7];
  const float* bv  = (const float*)d_in[8];
  const float* wo  = (const float*)d_in[9];
  const float* bo  = (const float*)d_in[10];
  float* out = (float*)d_out;

  const size_t EB = 2097152;  // elems per batch in a [4096,512] buffer

  char* base = (char*)d_ws;
  unsigned short* h_t  = (unsigned short*)base;                    // 67,108,864 B
  unsigned short* wqb  = (unsigned short*)(base + 67108864);       // 4 x 524,288 B
  unsigned short* wkb  = wqb + 262144;
  unsigned short* wvb  = wkb + 262144;
  unsigned short* wob  = wvb + 262144;
  float*          stats = (float*)(base + 69206016);               // 4,096 B
  char*           dyn   = base + 69210112;
  size_t rem = ws_size > 69210112 ? ws_size - 69210112 : 0;

  // per-batch dynamic bytes: q+k+v (3 x 4 MiB) + S (32 MiB) = 46,137,344
  int nb = 1;
  if      (rem >= (size_t)16 * 46137344) nb = 16;
  else if (rem >= (size_t)8  * 46137344) nb = 8;
  else if (rem >= (size_t)4  * 46137344) nb = 4;
  else if (rem >= (size_t)2  * 46137344) nb = 2;

  unsigned short* q  = (unsigned short*)dyn;
  unsigned short* kb = q  + (size_t)nb * EB;
  unsigned short* vb = kb + (size_t)nb * EB;
  unsigned short* Sb = (unsigned short*)(dyn + (size_t)nb * 3 * 4194304);
  unsigned short* attn = q;  // alias: q dead after S-GEMM within a chunk

  gn_stats<<<512, 256, 0, stream>>>(x, stats);
  gn_apply<<<dim3(64, 4, 16), 256, 0, stream>>>(x, stats, gnw, gnb, h_t);
  cvt_f32_bf16<<<256, 256, 0, stream>>>(wq, wqb);
  cvt_f32_bf16<<<256, 256, 0, stream>>>(wk, wkb);
  cvt_f32_bf16<<<256, 256, 0, stream>>>(wv, wvb);
  cvt_f32_bf16<<<256, 256, 0, stream>>>(wo, wob);

  const float sm_scale = 0.044194173824159216f;  // 1/sqrt(512)

  for (int b0 = 0; b0 < 16; b0 += nb) {
    const unsigned short* hc = h_t + (size_t)b0 * EB;
    // Q = h_t x wq^T  -> [tok, o] token-major
    gemm_nt<2, 0, unsigned short><<<dim3(4, 32, nb), 256, 0, stream>>>(
        hc, wqb, q, bq, nullptr, 4096, 512, 512, (long long)EB, 0, (long long)EB, 0, 1.f);
    gemm_nt<2, 0, unsigned short><<<dim3(4, 32, nb), 256, 0, stream>>>(
        hc, wkb, kb, bk, nullptr, 4096, 512, 512, (long long)EB, 0, (long long)EB, 0, 1.f);
    // V = wv x h_t^T -> [o, tok] channel-major
    gemm_nt<1, 0, unsigned short><<<dim3(32, 4, nb), 256, 0, stream>>>(
        wvb, hc, vb, bv, nullptr, 512, 4096, 512, 0, (long long)EB, (long long)EB, 0, 1.f);
    // S = Q K^T * scale  [4096, 4096]
    gemm_nt<0, 0, unsigned short><<<dim3(32, 32, nb), 256, 0, stream>>>(
        q, kb, Sb, nullptr, nullptr, 4096, 4096, 512,
        (long long)EB, (long long)EB, 16777216LL, 0, sm_scale);
    softmax_rows<<<nb * 4096, 256, 0, stream>>>(Sb);
    // attn = P x V^T -> [tok, c] token-major (writes over q region)
    gemm_nt<0, 0, unsigned short><<<dim3(4, 32, nb), 256, 0, stream>>>(
        Sb, vb, attn, nullptr, nullptr, 4096, 512, 4096,
        16777216LL, (long long)EB, (long long)EB, 0, 1.f);
    // out = wo x attn^T + bo + x  [o, tok] fp32
    gemm_nt<1, 1, float><<<dim3(32, 4, nb), 256, 0, stream>>>(
        wob, attn, out + (size_t)b0 * EB, bo, x + (size_t)b0 * EB,
        512, 4096, 512, 0, (long long)EB, (long long)EB, (long long)EB, 1.f);
  }
}

// Round 2
// 1652.736 us; speedup vs baseline: 1.0269x; 1.0269x over previous
//
#include <hip/hip_runtime.h>
#include <stdint.h>

// ---------- types ----------
typedef __bf16 bf16x8 __attribute__((ext_vector_type(8)));
typedef float  f32x4  __attribute__((ext_vector_type(4)));
typedef unsigned short ushortx8 __attribute__((ext_vector_type(8)));
typedef unsigned short ushortx4 __attribute__((ext_vector_type(4)));

#define DEVI __device__ __forceinline__

DEVI unsigned short f2bf(float f) {
  union { float f; unsigned int u; } v; v.f = f;
  unsigned int r = v.u + 0x7fffu + ((v.u >> 16) & 1u);
  return (unsigned short)(r >> 16);
}
DEVI float bf2f(unsigned short h) {
  union { unsigned int u; float f; } v; v.u = ((unsigned int)h) << 16;
  return v.f;
}

// async global->LDS, 16B per lane (m97 structure)
DEVI void gl_lds16(const unsigned short* g, unsigned short* l) {
  __builtin_amdgcn_global_load_lds(
      (__attribute__((address_space(1))) unsigned int*)g,
      (__attribute__((address_space(3))) unsigned int*)l,
      16, 0, 0);
}

DEVI void store_out(float* p, float v) { *p = v; }
DEVI void store_out(unsigned short* p, float v) { *p = f2bf(v); }

// ---------- GroupNorm stats: one block per (batch, group) ----------
__global__ __launch_bounds__(256) void gn_stats(const float* __restrict__ x,
                                                float* __restrict__ stats) {
  const int bg = blockIdx.x;
  const float* p = x + (size_t)bg * 65536;
  const int tid = threadIdx.x;
  float s = 0.f, ss = 0.f;
#pragma unroll 4
  for (int i = 0; i < 64; ++i) {
    float4 v = *(const float4*)(p + (((size_t)i * 256 + tid) << 2));
    s  += v.x + v.y + v.z + v.w;
    ss += v.x * v.x + v.y * v.y + v.z * v.z + v.w * v.w;
  }
  for (int off = 32; off; off >>= 1) { s += __shfl_xor(s, off); ss += __shfl_xor(ss, off); }
  __shared__ float rs[4], rss[4];
  const int lane = tid & 63, wave = tid >> 6;
  if (lane == 0) { rs[wave] = s; rss[wave] = ss; }
  __syncthreads();
  if (tid == 0) {
    float S1 = rs[0] + rs[1] + rs[2] + rs[3];
    float S2 = rss[0] + rss[1] + rss[2] + rss[3];
    float mean = S1 * (1.f / 65536.f);
    float var  = S2 * (1.f / 65536.f) - mean * mean;
    stats[bg * 2 + 0] = mean;
    stats[bg * 2 + 1] = rsqrtf(var + 1e-5f);
  }
}

// ---------- GN apply + transpose to token-major bf16 h_t[B,4096,512] ----------
__global__ __launch_bounds__(256) void gn_apply(const float* __restrict__ x,
                                                const float* __restrict__ stats,
                                                const float* __restrict__ gamma,
                                                const float* __restrict__ beta,
                                                unsigned short* __restrict__ h_t) {
  __shared__ alignas(16) unsigned short tile[64 * 136];
  const int tid = threadIdx.x;
  const int t0 = blockIdx.x * 64;
  const int c0 = blockIdx.y * 128;
  const int b  = blockIdx.z;
  const float* xb = x + ((size_t)b * 512 + c0) * 4096 + t0;
#pragma unroll
  for (int j = 0; j < 8; ++j) {
    int f = tid + j * 256;
    int r = f >> 4;
    int tc = (f & 15) << 2;
    float4 v = *(const float4*)(xb + (size_t)r * 4096 + tc);
    int ch = c0 + r;
    int g = ch >> 4;
    float mean = stats[((size_t)b * 32 + g) * 2 + 0];
    float rstd = stats[((size_t)b * 32 + g) * 2 + 1];
    float ga = gamma[ch] * rstd;
    float be = beta[ch] - mean * ga;
    tile[(tc + 0) * 136 + r] = f2bf(v.x * ga + be);
    tile[(tc + 1) * 136 + r] = f2bf(v.y * ga + be);
    tile[(tc + 2) * 136 + r] = f2bf(v.z * ga + be);
    tile[(tc + 3) * 136 + r] = f2bf(v.w * ga + be);
  }
  __syncthreads();
  unsigned short* hb = h_t + (size_t)b * 4096 * 512;
#pragma unroll
  for (int j = 0; j < 4; ++j) {
    int f = tid + j * 256;
    int tok = f >> 4;
    int cc = (f & 15) << 3;
    ushortx8 v = *(const ushortx8*)&tile[tok * 136 + cc];
    *(ushortx8*)(hb + (size_t)(t0 + tok) * 512 + c0 + cc) = v;
  }
}

// ---------- fp32 -> bf16 weight convert ----------
__global__ __launch_bounds__(256) void cvt_f32_bf16(const float* __restrict__ s,
                                                    unsigned short* __restrict__ d) {
  int i = (blockIdx.x * 256 + threadIdx.x) * 4;
  float4 v = *(const float4*)(s + i);
  ushortx4 o;
  o[0] = f2bf(v.x); o[1] = f2bf(v.y); o[2] = f2bf(v.z); o[3] = f2bf(v.w);
  *(ushortx4*)(d + i) = o;
}

// ---------- NT-form MFMA GEMM: D[m,n] = alpha * sum_k A[m,k]*B[n,k] (+bias)(+resid)
// BATCH-FIRST grid: blockIdx.x = batch (XCD affinity: lin%8 == batch when nb==8),
// blockIdx.y = bn, blockIdx.z = bm.
template <int BIAS_MODE, int RESID, typename OT>
__global__ __launch_bounds__(256) void gemm_nt(
    const unsigned short* __restrict__ A, const unsigned short* __restrict__ B,
    OT* __restrict__ D, const float* __restrict__ bias,
    const float* __restrict__ resid, int M, int N, int K,
    long long sA, long long sB, long long sD, long long sR, float alpha) {
  __shared__ alignas(16) unsigned short As[128 * 32];
  __shared__ alignas(16) unsigned short Bs[128 * 32];

  const int tid = threadIdx.x;
  const int bz = blockIdx.x, bn = blockIdx.y, bm = blockIdx.z;
  const unsigned short* Ab = A + (size_t)bz * sA + (size_t)bm * 128 * K;
  const unsigned short* Bb = B + (size_t)bz * sB + (size_t)bn * 128 * K;

  const int lane = tid & 63, wave = tid >> 6;
  const int wr = (wave >> 1) * 64, wc = (wave & 1) * 64;
  const int quad = lane >> 4, ln = lane & 15;

  const int r0 = tid >> 2, r1 = (tid + 256) >> 2;
  const int cc = (tid & 3) << 3;

  f32x4 acc[4][4] = {};

  const int KT = K >> 5;
  for (int kt = 0; kt < KT; ++kt) {
    const size_t k0 = (size_t)kt << 5;
    const unsigned short* ag = Ab + k0;
    const unsigned short* bg = Bb + k0;
    gl_lds16(ag + (size_t)r0 * K + cc, &As[(size_t)tid << 3]);
    gl_lds16(ag + (size_t)r1 * K + cc, &As[(size_t)(tid + 256) << 3]);
    gl_lds16(bg + (size_t)r0 * K + cc, &Bs[(size_t)tid << 3]);
    gl_lds16(bg + (size_t)r1 * K + cc, &Bs[(size_t)(tid + 256) << 3]);
    __builtin_amdgcn_s_waitcnt(0);
    __syncthreads();

    bf16x8 af[4], bq[4];
#pragma unroll
    for (int mi = 0; mi < 4; ++mi)
      af[mi] = *(const bf16x8*)&As[(wr + mi * 16 + ln) * 32 + quad * 8];
#pragma unroll
    for (int ni = 0; ni < 4; ++ni)
      bq[ni] = *(const bf16x8*)&Bs[(wc + ni * 16 + ln) * 32 + quad * 8];
#pragma unroll
    for (int mi = 0; mi < 4; ++mi)
#pragma unroll
      for (int ni = 0; ni < 4; ++ni)
        acc[mi][ni] = __builtin_amdgcn_mfma_f32_16x16x32_bf16(af[mi], bq[ni],
                                                              acc[mi][ni], 0, 0, 0);
    __syncthreads();
  }

  OT* Db = D + (size_t)bz * sD;
  const float* Rb = RESID ? (resid + (size_t)bz * sR) : nullptr;
#pragma unroll
  for (int mi = 0; mi < 4; ++mi) {
#pragma unroll
    for (int ni = 0; ni < 4; ++ni) {
#pragma unroll
      for (int r = 0; r < 4; ++r) {
        int row = bm * 128 + wr + mi * 16 + quad * 4 + r;
        int col = bn * 128 + wc + ni * 16 + ln;
        float v = acc[mi][ni][r] * alpha;
        if (BIAS_MODE == 1) v += bias[row];
        if (BIAS_MODE == 2) v += bias[col];
        size_t idx = (size_t)row * N + col;
        if (RESID) v += Rb[idx];
        store_out(&Db[idx], v);
      }
    }
  }
}

// ---------- row softmax over 4096 bf16, in place ----------
__global__ __launch_bounds__(256) void softmax_rows(unsigned short* __restrict__ S) {
  const int tid = threadIdx.x;
  unsigned short* p = S + (size_t)blockIdx.x * 4096 + tid * 16;
  ushortx8 u0 = *(const ushortx8*)p;
  ushortx8 u1 = *(const ushortx8*)(p + 8);
  float v[16];
#pragma unroll
  for (int i = 0; i < 8; ++i) { v[i] = bf2f(u0[i]); v[i + 8] = bf2f(u1[i]); }
  float m = v[0];
#pragma unroll
  for (int i = 1; i < 16; ++i) m = fmaxf(m, v[i]);
  for (int off = 32; off; off >>= 1) m = fmaxf(m, __shfl_xor(m, off));
  __shared__ float red[4];
  __shared__ float red2[4];
  const int lane = tid & 63, wave = tid >> 6;
  if (lane == 0) red[wave] = m;
  __syncthreads();
  m = fmaxf(fmaxf(red[0], red[1]), fmaxf(red[2], red[3]));
  float s = 0.f;
#pragma unroll
  for (int i = 0; i < 16; ++i) { v[i] = __expf(v[i] - m); s += v[i]; }
  for (int off = 32; off; off >>= 1) s += __shfl_xor(s, off);
  if (lane == 0) red2[wave] = s;
  __syncthreads();
  s = red2[0] + red2[1] + red2[2] + red2[3];
  float inv = 1.f / s;
#pragma unroll
  for (int i = 0; i < 8; ++i) { u0[i] = f2bf(v[i] * inv); u1[i] = f2bf(v[i + 8] * inv); }
  *(ushortx8*)p = u0;
  *(ushortx8*)(p + 8) = u1;
}

// ---------- host ----------
extern "C" void kernel_launch(void* const* d_in, const int* in_sizes, int n_in,
                              void* d_out, int out_size, void* d_ws, size_t ws_size,
                              hipStream_t stream) {
  const float* x   = (const float*)d_in[0];
  const float* gnw = (const float*)d_in[1];
  const float* gnb = (const float*)d_in[2];
  const float* wq  = (const float*)d_in[3];
  const float* bq  = (const float*)d_in[4];
  const float* wk  = (const float*)d_in[5];
  const float* bk  = (const float*)d_in[6];
  const float* wv  = (const float*)d_in[7];
  const float* bv  = (const float*)d_in[8];
  const float* wo  = (const float*)d_in[9];
  const float* bo  = (const float*)d_in[10];
  float* out = (float*)d_out;

  const size_t EB = 2097152;  // elems per batch in a [4096,512] buffer

  char* base = (char*)d_ws;
  unsigned short* h_t  = (unsigned short*)base;                    // 67,108,864 B
  unsigned short* wqb  = (unsigned short*)(base + 67108864);
  unsigned short* wkb  = wqb + 262144;
  unsigned short* wvb  = wkb + 262144;
  unsigned short* wob  = wvb + 262144;
  float*          stats = (float*)(base + 69206016);
  char*           dyn   = base + 69210112;
  size_t rem = ws_size > 69210112 ? ws_size - 69210112 : 0;

  // per-batch dynamic bytes: q+k+v (3 x 4 MiB) + S (32 MiB)
  int nb = 1;
  if      (rem >= (size_t)16 * 46137344) nb = 16;
  else if (rem >= (size_t)8  * 46137344) nb = 8;
  else if (rem >= (size_t)4  * 46137344) nb = 4;
  else if (rem >= (size_t)2  * 46137344) nb = 2;

  unsigned short* q  = (unsigned short*)dyn;
  unsigned short* kb = q  + (size_t)nb * EB;
  unsigned short* vb = kb + (size_t)nb * EB;
  unsigned short* Sb = (unsigned short*)(dyn + (size_t)nb * 3 * 4194304);
  unsigned short* attn = q;  // alias: q dead after S-GEMM within a chunk

  gn_stats<<<512, 256, 0, stream>>>(x, stats);
  gn_apply<<<dim3(64, 4, 16), 256, 0, stream>>>(x, stats, gnw, gnb, h_t);
  cvt_f32_bf16<<<256, 256, 0, stream>>>(wq, wqb);
  cvt_f32_bf16<<<256, 256, 0, stream>>>(wk, wkb);
  cvt_f32_bf16<<<256, 256, 0, stream>>>(wv, wvb);
  cvt_f32_bf16<<<256, 256, 0, stream>>>(wo, wob);

  const float sm_scale = 0.044194173824159216f;  // 1/sqrt(512)

  for (int b0 = 0; b0 < 16; b0 += nb) {
    const unsigned short* hc = h_t + (size_t)b0 * EB;
    // Q = h_t x wq^T  -> [tok, o] token-major   (grid: batch, bn, bm)
    gemm_nt<2, 0, unsigned short><<<dim3(nb, 4, 32), 256, 0, stream>>>(
        hc, wqb, q, bq, nullptr, 4096, 512, 512, (long long)EB, 0, (long long)EB, 0, 1.f);
    gemm_nt<2, 0, unsigned short><<<dim3(nb, 4, 32), 256, 0, stream>>>(
        hc, wkb, kb, bk, nullptr, 4096, 512, 512, (long long)EB, 0, (long long)EB, 0, 1.f);
    // V = wv x h_t^T -> [o, tok] channel-major
    gemm_nt<1, 0, unsigned short><<<dim3(nb, 32, 4), 256, 0, stream>>>(
        wvb, hc, vb, bv, nullptr, 512, 4096, 512, 0, (long long)EB, (long long)EB, 0, 1.f);
    // S = Q K^T * scale  [4096, 4096]
    gemm_nt<0, 0, unsigned short><<<dim3(nb, 32, 32), 256, 0, stream>>>(
        q, kb, Sb, nullptr, nullptr, 4096, 4096, 512,
        (long long)EB, (long long)EB, 16777216LL, 0, sm_scale);
    softmax_rows<<<nb * 4096, 256, 0, stream>>>(Sb);
    // attn = P x V^T -> [tok, c] token-major (writes over q region)
    gemm_nt<0, 0, unsigned short><<<dim3(nb, 4, 32), 256, 0, stream>>>(
        Sb, vb, attn, nullptr, nullptr, 4096, 512, 4096,
        16777216LL, (long long)EB, (long long)EB, 0, 1.f);
    // out = wo x attn^T + bo + x  [o, tok] fp32
    gemm_nt<1, 1, float><<<dim3(nb, 32, 4), 256, 0, stream>>>(
        wob, attn, out + (size_t)b0 * EB, bo, x + (size_t)b0 * EB,
        512, 4096, 512, 0, (long long)EB, (long long)EB, (long long)EB, 1.f);
  }
}

// Round 3
// 1507.318 us; speedup vs baseline: 1.1259x; 1.0965x over previous
//
#include <hip/hip_runtime.h>
#include <stdint.h>

// ---------- types ----------
typedef __bf16 bf16x8 __attribute__((ext_vector_type(8)));
typedef float  f32x4  __attribute__((ext_vector_type(4)));
typedef unsigned short ushortx8 __attribute__((ext_vector_type(8)));
typedef unsigned short ushortx4 __attribute__((ext_vector_type(4)));

#define DEVI __device__ __forceinline__

DEVI unsigned short f2bf(float f) {
  union { float f; unsigned int u; } v; v.f = f;
  unsigned int r = v.u + 0x7fffu + ((v.u >> 16) & 1u);
  return (unsigned short)(r >> 16);
}
DEVI float bf2f(unsigned short h) {
  union { unsigned int u; float f; } v; v.u = ((unsigned int)h) << 16;
  return v.f;
}

// async global->LDS, 16B per lane (m97 structure)
DEVI void gl_lds16(const unsigned short* g, unsigned short* l) {
  __builtin_amdgcn_global_load_lds(
      (__attribute__((address_space(1))) unsigned int*)g,
      (__attribute__((address_space(3))) unsigned int*)l,
      16, 0, 0);
}

// raw barrier WITHOUT the __syncthreads fence (which forces vmcnt(0) drain).
// Hardware waitcnt discipline is handled manually with s_waitcnt immediates.
DEVI void raw_barrier() {
  asm volatile("" ::: "memory");
  __builtin_amdgcn_s_barrier();
  asm volatile("" ::: "memory");
}
// s_waitcnt imm: vmcnt[3:0]|[15:14], expcnt[6:4], lgkmcnt[11:8]
#define WAITCNT_VM4 0x0F74  // vmcnt=4, exp/lgkm unconstrained
#define WAITCNT_VM0 0x0F70  // vmcnt=0

DEVI void store_out(float* p, float v) { *p = v; }
DEVI void store_out(unsigned short* p, float v) { *p = f2bf(v); }

// ---------- GroupNorm stats: one block per (batch, group) ----------
__global__ __launch_bounds__(256) void gn_stats(const float* __restrict__ x,
                                                float* __restrict__ stats) {
  const int bg = blockIdx.x;
  const float* p = x + (size_t)bg * 65536;
  const int tid = threadIdx.x;
  float s = 0.f, ss = 0.f;
#pragma unroll 4
  for (int i = 0; i < 64; ++i) {
    float4 v = *(const float4*)(p + (((size_t)i * 256 + tid) << 2));
    s  += v.x + v.y + v.z + v.w;
    ss += v.x * v.x + v.y * v.y + v.z * v.z + v.w * v.w;
  }
  for (int off = 32; off; off >>= 1) { s += __shfl_xor(s, off); ss += __shfl_xor(ss, off); }
  __shared__ float rs[4], rss[4];
  const int lane = tid & 63, wave = tid >> 6;
  if (lane == 0) { rs[wave] = s; rss[wave] = ss; }
  __syncthreads();
  if (tid == 0) {
    float S1 = rs[0] + rs[1] + rs[2] + rs[3];
    float S2 = rss[0] + rss[1] + rss[2] + rss[3];
    float mean = S1 * (1.f / 65536.f);
    float var  = S2 * (1.f / 65536.f) - mean * mean;
    stats[bg * 2 + 0] = mean;
    stats[bg * 2 + 1] = rsqrtf(var + 1e-5f);
  }
}

// ---------- GN apply + transpose to token-major bf16 h_t[B,4096,512] ----------
__global__ __launch_bounds__(256) void gn_apply(const float* __restrict__ x,
                                                const float* __restrict__ stats,
                                                const float* __restrict__ gamma,
                                                const float* __restrict__ beta,
                                                unsigned short* __restrict__ h_t) {
  __shared__ alignas(16) unsigned short tile[64 * 136];
  const int tid = threadIdx.x;
  const int t0 = blockIdx.x * 64;
  const int c0 = blockIdx.y * 128;
  const int b  = blockIdx.z;
  const float* xb = x + ((size_t)b * 512 + c0) * 4096 + t0;
#pragma unroll
  for (int j = 0; j < 8; ++j) {
    int f = tid + j * 256;
    int r = f >> 4;
    int tc = (f & 15) << 2;
    float4 v = *(const float4*)(xb + (size_t)r * 4096 + tc);
    int ch = c0 + r;
    int g = ch >> 4;
    float mean = stats[((size_t)b * 32 + g) * 2 + 0];
    float rstd = stats[((size_t)b * 32 + g) * 2 + 1];
    float ga = gamma[ch] * rstd;
    float be = beta[ch] - mean * ga;
    tile[(tc + 0) * 136 + r] = f2bf(v.x * ga + be);
    tile[(tc + 1) * 136 + r] = f2bf(v.y * ga + be);
    tile[(tc + 2) * 136 + r] = f2bf(v.z * ga + be);
    tile[(tc + 3) * 136 + r] = f2bf(v.w * ga + be);
  }
  __syncthreads();
  unsigned short* hb = h_t + (size_t)b * 4096 * 512;
#pragma unroll
  for (int j = 0; j < 4; ++j) {
    int f = tid + j * 256;
    int tok = f >> 4;
    int cc = (f & 15) << 3;
    ushortx8 v = *(const ushortx8*)&tile[tok * 136 + cc];
    *(ushortx8*)(hb + (size_t)(t0 + tok) * 512 + c0 + cc) = v;
  }
}

// ---------- fp32 -> bf16 weight convert ----------
__global__ __launch_bounds__(256) void cvt_f32_bf16(const float* __restrict__ s,
                                                    unsigned short* __restrict__ d) {
  int i = (blockIdx.x * 256 + threadIdx.x) * 4;
  float4 v = *(const float4*)(s + i);
  ushortx4 o;
  o[0] = f2bf(v.x); o[1] = f2bf(v.y); o[2] = f2bf(v.z); o[3] = f2bf(v.w);
  *(ushortx4*)(d + i) = o;
}

// ---------- NT-form MFMA GEMM, double-buffered LDS, raw barriers ----------
// D[m,n] = alpha * sum_k A[m,k]*B[n,k] (+bias)(+resid)
// grid: (batch, bn, bm) — batch fastest for XCD L2 affinity.
template <int BIAS_MODE, int RESID, typename OT>
__global__ __launch_bounds__(256) void gemm_nt(
    const unsigned short* __restrict__ A, const unsigned short* __restrict__ B,
    OT* __restrict__ D, const float* __restrict__ bias,
    const float* __restrict__ resid, int M, int N, int K,
    long long sA, long long sB, long long sD, long long sR, float alpha) {
  __shared__ alignas(16) unsigned short As[2][128 * 32];
  __shared__ alignas(16) unsigned short Bs[2][128 * 32];

  const int tid = threadIdx.x;
  const int bz = blockIdx.x, bn = blockIdx.y, bm = blockIdx.z;
  const unsigned short* Ab = A + (size_t)bz * sA + (size_t)bm * 128 * K;
  const unsigned short* Bb = B + (size_t)bz * sB + (size_t)bn * 128 * K;

  const int lane = tid & 63, wave = tid >> 6;
  const int wr = (wave >> 1) * 64, wc = (wave & 1) * 64;
  const int quad = lane >> 4, ln = lane & 15;

  const int r0 = tid >> 2, r1 = (tid + 256) >> 2;
  const int cc = (tid & 3) << 3;

  // per-thread LDS staging offsets (wave-uniform base + lane*16B, required)
  unsigned short* l0a[2] = { &As[0][(size_t)tid << 3], &As[1][(size_t)tid << 3] };
  unsigned short* l1a[2] = { &As[0][(size_t)(tid + 256) << 3], &As[1][(size_t)(tid + 256) << 3] };
  unsigned short* l0b[2] = { &Bs[0][(size_t)tid << 3], &Bs[1][(size_t)tid << 3] };
  unsigned short* l1b[2] = { &Bs[0][(size_t)(tid + 256) << 3], &Bs[1][(size_t)(tid + 256) << 3] };

  f32x4 acc[4][4] = {};

  const int KT = K >> 5;

  // stage tile 0 into buf 0
  {
    const unsigned short* ag = Ab;
    const unsigned short* bg = Bb;
    gl_lds16(ag + (size_t)r0 * K + cc, l0a[0]);
    gl_lds16(ag + (size_t)r1 * K + cc, l1a[0]);
    gl_lds16(bg + (size_t)r0 * K + cc, l0b[0]);
    gl_lds16(bg + (size_t)r1 * K + cc, l1b[0]);
  }

  int kt = 0;
  for (; kt < KT - 1; ++kt) {
    const int cur = kt & 1, nxt = cur ^ 1;
    // issue next tile's loads BEFORE waiting — they stay in flight across the barrier
    {
      const size_t k0 = (size_t)(kt + 1) << 5;
      const unsigned short* ag = Ab + k0;
      const unsigned short* bg = Bb + k0;
      gl_lds16(ag + (size_t)r0 * K + cc, l0a[nxt]);
      gl_lds16(ag + (size_t)r1 * K + cc, l1a[nxt]);
      gl_lds16(bg + (size_t)r0 * K + cc, l0b[nxt]);
      gl_lds16(bg + (size_t)r1 * K + cc, l1b[nxt]);
    }
    __builtin_amdgcn_s_waitcnt(WAITCNT_VM4);  // current tile's 4 loads done
    raw_barrier();

    bf16x8 af[4], bq[4];
#pragma unroll
    for (int mi = 0; mi < 4; ++mi)
      af[mi] = *(const bf16x8*)&As[cur][(wr + mi * 16 + ln) * 32 + quad * 8];
#pragma unroll
    for (int ni = 0; ni < 4; ++ni)
      bq[ni] = *(const bf16x8*)&Bs[cur][(wc + ni * 16 + ln) * 32 + quad * 8];
#pragma unroll
    for (int mi = 0; mi < 4; ++mi)
#pragma unroll
      for (int ni = 0; ni < 4; ++ni)
        acc[mi][ni] = __builtin_amdgcn_mfma_f32_16x16x32_bf16(af[mi], bq[ni],
                                                              acc[mi][ni], 0, 0, 0);
    raw_barrier();  // all waves done reading buf cur before it is restaged at kt+2
  }

  // last tile
  {
    const int cur = kt & 1;
    __builtin_amdgcn_s_waitcnt(WAITCNT_VM0);
    raw_barrier();
    bf16x8 af[4], bq[4];
#pragma unroll
    for (int mi = 0; mi < 4; ++mi)
      af[mi] = *(const bf16x8*)&As[cur][(wr + mi * 16 + ln) * 32 + quad * 8];
#pragma unroll
    for (int ni = 0; ni < 4; ++ni)
      bq[ni] = *(const bf16x8*)&Bs[cur][(wc + ni * 16 + ln) * 32 + quad * 8];
#pragma unroll
    for (int mi = 0; mi < 4; ++mi)
#pragma unroll
      for (int ni = 0; ni < 4; ++ni)
        acc[mi][ni] = __builtin_amdgcn_mfma_f32_16x16x32_bf16(af[mi], bq[ni],
                                                              acc[mi][ni], 0, 0, 0);
  }

  OT* Db = D + (size_t)bz * sD;
  const float* Rb = RESID ? (resid + (size_t)bz * sR) : nullptr;
#pragma unroll
  for (int mi = 0; mi < 4; ++mi) {
#pragma unroll
    for (int ni = 0; ni < 4; ++ni) {
#pragma unroll
      for (int r = 0; r < 4; ++r) {
        int row = bm * 128 + wr + mi * 16 + quad * 4 + r;
        int col = bn * 128 + wc + ni * 16 + ln;
        float v = acc[mi][ni][r] * alpha;
        if (BIAS_MODE == 1) v += bias[row];
        if (BIAS_MODE == 2) v += bias[col];
        size_t idx = (size_t)row * N + col;
        if (RESID) v += Rb[idx];
        store_out(&Db[idx], v);
      }
    }
  }
}

// ---------- row softmax over 4096 bf16, in place ----------
__global__ __launch_bounds__(256) void softmax_rows(unsigned short* __restrict__ S) {
  const int tid = threadIdx.x;
  unsigned short* p = S + (size_t)blockIdx.x * 4096 + tid * 16;
  ushortx8 u0 = *(const ushortx8*)p;
  ushortx8 u1 = *(const ushortx8*)(p + 8);
  float v[16];
#pragma unroll
  for (int i = 0; i < 8; ++i) { v[i] = bf2f(u0[i]); v[i + 8] = bf2f(u1[i]); }
  float m = v[0];
#pragma unroll
  for (int i = 1; i < 16; ++i) m = fmaxf(m, v[i]);
  for (int off = 32; off; off >>= 1) m = fmaxf(m, __shfl_xor(m, off));
  __shared__ float red[4];
  __shared__ float red2[4];
  const int lane = tid & 63, wave = tid >> 6;
  if (lane == 0) red[wave] = m;
  __syncthreads();
  m = fmaxf(fmaxf(red[0], red[1]), fmaxf(red[2], red[3]));
  float s = 0.f;
#pragma unroll
  for (int i = 0; i < 16; ++i) { v[i] = __expf(v[i] - m); s += v[i]; }
  for (int off = 32; off; off >>= 1) s += __shfl_xor(s, off);
  if (lane == 0) red2[wave] = s;
  __syncthreads();
  s = red2[0] + red2[1] + red2[2] + red2[3];
  float inv = 1.f / s;
#pragma unroll
  for (int i = 0; i < 8; ++i) { u0[i] = f2bf(v[i] * inv); u1[i] = f2bf(v[i + 8] * inv); }
  *(ushortx8*)p = u0;
  *(ushortx8*)(p + 8) = u1;
}

// ---------- host ----------
extern "C" void kernel_launch(void* const* d_in, const int* in_sizes, int n_in,
                              void* d_out, int out_size, void* d_ws, size_t ws_size,
                              hipStream_t stream) {
  const float* x   = (const float*)d_in[0];
  const float* gnw = (const float*)d_in[1];
  const float* gnb = (const float*)d_in[2];
  const float* wq  = (const float*)d_in[3];
  const float* bq  = (const float*)d_in[4];
  const float* wk  = (const float*)d_in[5];
  const float* bk  = (const float*)d_in[6];
  const float* wv  = (const float*)d_in[7];
  const float* bv  = (const float*)d_in[8];
  const float* wo  = (const float*)d_in[9];
  const float* bo  = (const float*)d_in[10];
  float* out = (float*)d_out;

  const size_t EB = 2097152;  // elems per batch in a [4096,512] buffer

  char* base = (char*)d_ws;
  unsigned short* h_t  = (unsigned short*)base;                    // 67,108,864 B
  unsigned short* wqb  = (unsigned short*)(base + 67108864);
  unsigned short* wkb  = wqb + 262144;
  unsigned short* wvb  = wkb + 262144;
  unsigned short* wob  = wvb + 262144;
  float*          stats = (float*)(base + 69206016);
  char*           dyn   = base + 69210112;
  size_t rem = ws_size > 69210112 ? ws_size - 69210112 : 0;

  // per-batch dynamic bytes: q+k+v (3 x 4 MiB) + S (32 MiB)
  int nb = 1;
  if      (rem >= (size_t)16 * 46137344) nb = 16;
  else if (rem >= (size_t)8  * 46137344) nb = 8;
  else if (rem >= (size_t)4  * 46137344) nb = 4;
  else if (rem >= (size_t)2  * 46137344) nb = 2;

  unsigned short* q  = (unsigned short*)dyn;
  unsigned short* kb = q  + (size_t)nb * EB;
  unsigned short* vb = kb + (size_t)nb * EB;
  unsigned short* Sb = (unsigned short*)(dyn + (size_t)nb * 3 * 4194304);
  unsigned short* attn = q;  // alias: q dead after S-GEMM within a chunk

  gn_stats<<<512, 256, 0, stream>>>(x, stats);
  gn_apply<<<dim3(64, 4, 16), 256, 0, stream>>>(x, stats, gnw, gnb, h_t);
  cvt_f32_bf16<<<256, 256, 0, stream>>>(wq, wqb);
  cvt_f32_bf16<<<256, 256, 0, stream>>>(wk, wkb);
  cvt_f32_bf16<<<256, 256, 0, stream>>>(wv, wvb);
  cvt_f32_bf16<<<256, 256, 0, stream>>>(wo, wob);

  const float sm_scale = 0.044194173824159216f;  // 1/sqrt(512)

  for (int b0 = 0; b0 < 16; b0 += nb) {
    const unsigned short* hc = h_t + (size_t)b0 * EB;
    // Q = h_t x wq^T  -> [tok, o] token-major   (grid: batch, bn, bm)
    gemm_nt<2, 0, unsigned short><<<dim3(nb, 4, 32), 256, 0, stream>>>(
        hc, wqb, q, bq, nullptr, 4096, 512, 512, (long long)EB, 0, (long long)EB, 0, 1.f);
    gemm_nt<2, 0, unsigned short><<<dim3(nb, 4, 32), 256, 0, stream>>>(
        hc, wkb, kb, bk, nullptr, 4096, 512, 512, (long long)EB, 0, (long long)EB, 0, 1.f);
    // V = wv x h_t^T -> [o, tok] channel-major
    gemm_nt<1, 0, unsigned short><<<dim3(nb, 32, 4), 256, 0, stream>>>(
        wvb, hc, vb, bv, nullptr, 512, 4096, 512, 0, (long long)EB, (long long)EB, 0, 1.f);
    // S = Q K^T * scale  [4096, 4096]
    gemm_nt<0, 0, unsigned short><<<dim3(nb, 32, 32), 256, 0, stream>>>(
        q, kb, Sb, nullptr, nullptr, 4096, 4096, 512,
        (long long)EB, (long long)EB, 16777216LL, 0, sm_scale);
    softmax_rows<<<nb * 4096, 256, 0, stream>>>(Sb);
    // attn = P x V^T -> [tok, c] token-major (writes over q region)
    gemm_nt<0, 0, unsigned short><<<dim3(nb, 4, 32), 256, 0, stream>>>(
        Sb, vb, attn, nullptr, nullptr, 4096, 512, 4096,
        16777216LL, (long long)EB, (long long)EB, 0, 1.f);
    // out = wo x attn^T + bo + x  [o, tok] fp32
    gemm_nt<1, 1, float><<<dim3(nb, 32, 4), 256, 0, stream>>>(
        wob, attn, out + (size_t)b0 * EB, bo, x + (size_t)b0 * EB,
        512, 4096, 512, 0, (long long)EB, (long long)EB, (long long)EB, 1.f);
  }
}